// Round 11
// baseline (32.359 us; speedup 1.0000x reference)
//
#include <hip/hip_runtime.h>
#include <hip/hip_bf16.h>

typedef __attribute__((ext_vector_type(8))) short bf16x8;
typedef __attribute__((ext_vector_type(4))) float f32x4;

#define EPS 1e-5f
#define K2L 2.8853900817779268f   // 2*log2(e): folds exp(2y) -> exp2(y*K2L)

// ws layout: frag blocks (182 x 1KB bf16) then fp32 ST region
#define N_FRAG_BLOCKS 182
#define WSB_LEAF 0      // 64 blocks: leaf l
#define WSB_MID  64     // 80 blocks: m*10 + tt*5 + s
#define WSB_ROOT 144    // 36 blocks: tt*9 + s
#define WSB_HEAD 180    // 2 blocks: s
#define ST_SL 0
#define ST_TL 1024
#define ST_SM 2048
#define ST_TM 2304
#define ST_SR 2560
#define ST_TR 2624
#define WS_ST_BYTE_OFF (N_FRAG_BLOCKS * 1024)

__device__ __forceinline__ unsigned short f2bf(float f) {  // RNE float->bf16
    unsigned u = __float_as_uint(f);
    unsigned r = u + 0x7fffu + ((u >> 16) & 1u);
    return (unsigned short)(r >> 16);
}

// compiler-friendly packed f32x2 -> bf16x2 (emits v_cvt_pk_bf16_f32)
__device__ __forceinline__ unsigned pk2(float a, float b) {
    float2 f2; f2.x = a; f2.y = b;
    __hip_bfloat162 h = __float22bfloat162_rn(f2);
    union { __hip_bfloat162 h2; unsigned u; } cv; cv.h2 = h;
    return cv.u;
}

__device__ __forceinline__ bf16x8 pack8(float4 a, float4 b) {
    union { unsigned u[4]; bf16x8 v; } r;
    r.u[0] = pk2(a.x, a.y); r.u[1] = pk2(a.z, a.w);
    r.u[2] = pk2(b.x, b.y); r.u[3] = pk2(b.z, b.w);
    return r.v;
}

// BN+tanh with pre-folded scale: arg = acc*S' + T' (S',T' carry 2*log2e)
__device__ __forceinline__ float bn_act(float acc, float Sp, float Tp) {
    float e = exp2f(fmaf(acc, Sp, Tp));
    float r = __builtin_amdgcn_rcpf(e + 1.0f);
    return fmaf(-2.0f, r, 1.0f);
}

// ---------------- prep: fragment-ordered bf16 weights + folded BN ----------
__global__ void ontology_prep(
    const float* __restrict__ Wl, const float* __restrict__ Wm,
    const float* __restrict__ Wr, const float* __restrict__ Wh,
    const float* __restrict__ bl, const float* __restrict__ gl,
    const float* __restrict__ betal, const float* __restrict__ ml,
    const float* __restrict__ vl,
    const float* __restrict__ bm, const float* __restrict__ gm,
    const float* __restrict__ betam, const float* __restrict__ mm,
    const float* __restrict__ vm,
    const float* __restrict__ br, const float* __restrict__ gr,
    const float* __restrict__ betar, const float* __restrict__ mr,
    const float* __restrict__ vr,
    unsigned short* __restrict__ wsFrag, float* __restrict__ wsST)
{
    const int b = blockIdx.x;
    const int t = threadIdx.x;
    if (b < N_FRAG_BLOCKS) {
        // A'-frag (transposed weights): lane t holds A'[row=t&15][k=(t>>4)*8+i]
        const int row = t & 15, g = t >> 4;
        unsigned short vals[8];
        #pragma unroll
        for (int i = 0; i < 8; ++i) {
            const int k = g * 8 + i;
            float v = 0.f;
            if (b < 64) {                       // leaf l: pair-packed K
                const int l = b;
                if ((l & 1) == 0) { if (k < 16)  v = Wl[l * 256 + k * 16 + row]; }
                else              { if (k >= 16) v = Wl[l * 256 + (k - 16) * 16 + row]; }
            } else if (b < 144) {               // mid: m*10 + tt*5 + s
                const int idx = b - 64, m = idx / 10, rem = idx % 10;
                const int tt = rem / 5, s = rem % 5;
                const int krow = s * 32 + k;
                if (krow < 144) v = Wm[m * 4608 + krow * 32 + tt * 16 + row];
            } else if (b < 180) {               // root: tt*9 + s
                const int idx = b - 144, tt = idx / 9, s = idx % 9;
                if (s == 0) { if (k < 16) v = Wr[k * 64 + tt * 16 + row]; }
                else { const int krow = 16 + (s - 1) * 32 + k;
                       v = Wr[krow * 64 + tt * 16 + row]; }
            } else {                            // head
                const int s = b - 180, krow = s * 32 + k;
                if (row < 10) v = Wh[krow * 10 + row];
            }
            vals[i] = f2bf(v);
        }
        #pragma unroll
        for (int i = 0; i < 8; ++i) wsFrag[b * 512 + t * 8 + i] = vals[i];
    } else if (b == N_FRAG_BLOCKS) {            // leaf ST (1024), folded by K2L
        for (int i = 0; i < 16; ++i) {
            const int id = t + 64 * i;
            const float S = gl[id] * rsqrtf(vl[id] + EPS);
            wsST[ST_SL + id] = S * K2L;
            wsST[ST_TL + id] = ((bl[id] - ml[id]) * S + betal[id]) * K2L;
        }
    } else if (b == N_FRAG_BLOCKS + 1) {        // mid ST (256)
        for (int i = 0; i < 4; ++i) {
            const int id = t + 64 * i;
            const float S = gm[id] * rsqrtf(vm[id] + EPS);
            wsST[ST_SM + id] = S * K2L;
            wsST[ST_TM + id] = ((bm[id] - mm[id]) * S + betam[id]) * K2L;
        }
    } else {                                     // root ST (64)
        const int id = t;
        const float S = gr[id] * rsqrtf(vr[id] + EPS);
        wsST[ST_SR + id] = S * K2L;
        wsST[ST_TR + id] = ((br[id] - mr[id]) * S + betar[id]) * K2L;
    }
}

// ---------------- main fused MFMA kernel: 1 mid per wave -------------------
// Block = 512 thr = 8 waves = one 16-sample tile; wave w owns mid w entirely
// (8 leaves -> mid -> hm in LDS). Root + head at the combine tail (waves 0..3
// read all 8 hm slabs as B-frags). 8192 waves = 32/CU = 8 waves/SIMD.
// LDS = 40960 B exact -> 4 blocks/CU. x loads STREAMED pair-wise and bf16
// packing via cvt_pk so peak VGPR fits the 64-reg cap (no scratch).
__global__ __launch_bounds__(512, 8) void ontology_mfma(
    const float* __restrict__ x,
    const unsigned short* __restrict__ wsFrag,
    const float* __restrict__ wsST,
    const float* __restrict__ bh,
    float* __restrict__ out)
{
    // per-wave region = 2560 u16 (5120 B): mid_in at w*2560 + c*160 + col.
    // hm[w] aliases own region cols 0..39 (written post own-mid reads).
    // hr aliases wave-7 region +1280 u16 (dead by then).
    __shared__ __align__(16) unsigned short lds[8 * 2560];   // 40960 B exact

    const int tid  = threadIdx.x;
    const int w    = tid >> 6;
    const int lane = tid & 63;
    const int c    = lane & 15;       // sample within tile
    const int g    = lane >> 4;       // k/feat group
    const int rowbase = blockIdx.x * 16;
    const float* xrow = x + (size_t)(rowbase + c) * 1168;

    unsigned short* my = lds + w * 2560;            // own region (u16 units)
    unsigned short* hr = lds + 7 * 2560 + 1280;     // [16][72] u16

    const float* Sl = wsST + ST_SL; const float* Tl = wsST + ST_TL;
    const float* Sm = wsST + ST_SM; const float* Tm = wsST + ST_TM;
    const float* Sr = wsST + ST_SR; const float* Tr = wsST + ST_TR;

    // zero own K-pad cols 144..159 (read by mid s=4)
    { uint2 z; z.x = 0u; z.y = 0u;
      *(uint2*)(my + c * 160 + 144 + 4 * g) = z; }

    // xm -> mid_in cols 0..15
    {
        float4 xm4 = *(const float4*)(xrow + 1024 + w * 16 + 4 * g);
        uint2 pm; pm.x = pk2(xm4.x, xm4.y); pm.y = pk2(xm4.z, xm4.w);
        *(uint2*)(my + c * 160 + 4 * g) = pm;
    }

    // ---- 8 leaves, x streamed pair-wise (low peak VGPR) ----
    #pragma unroll
    for (int p = 0; p < 4; ++p) {
        const float* a = xrow + (w * 4 + p) * 32 + g * 8;
        float4 xa = *(const float4*)a;
        float4 x2 = *(const float4*)(a + 4);
        bf16x8 bfrag = pack8(xa, x2);
        #pragma unroll
        for (int e = 0; e < 2; ++e) {
            const int l = 2 * p + e, leaf = w * 8 + l;
            bf16x8 afrag = *(const bf16x8*)(wsFrag + (WSB_LEAF + leaf) * 512 + lane * 8);
            f32x4 zz = {0.f,0.f,0.f,0.f};
            f32x4 acc = __builtin_amdgcn_mfma_f32_16x16x32_bf16(afrag, bfrag, zz, 0, 0, 0);
            const int po = leaf * 16 + 4 * g;
            float4 S = *(const float4*)(Sl + po);
            float4 T = *(const float4*)(Tl + po);
            uint2 pk;
            pk.x = pk2(bn_act(acc[0], S.x, T.x), bn_act(acc[1], S.y, T.y));
            pk.y = pk2(bn_act(acc[2], S.z, T.z), bn_act(acc[3], S.w, T.w));
            *(uint2*)(my + c * 160 + 16 + l * 16 + 4 * g) = pk;
        }
    }

    // ---- mid w: both col-tiles share each bfrag (5 ds_reads) ----
    {
        f32x4 acc0 = {0.f,0.f,0.f,0.f};
        f32x4 acc1 = {0.f,0.f,0.f,0.f};
        const unsigned short* fb = wsFrag + (WSB_MID + w * 10) * 512 + lane * 8;
        #pragma unroll
        for (int s = 0; s < 5; ++s) {
            bf16x8 bfrag = *(const bf16x8*)(my + c * 160 + s * 32 + g * 8);
            bf16x8 a0 = *(const bf16x8*)(fb + s * 512);
            bf16x8 a1 = *(const bf16x8*)(fb + (5 + s) * 512);
            acc0 = __builtin_amdgcn_mfma_f32_16x16x32_bf16(a0, bfrag, acc0, 0, 0, 0);
            acc1 = __builtin_amdgcn_mfma_f32_16x16x32_bf16(a1, bfrag, acc1, 0, 0, 0);
        }
        // hm[w] aliases own region cols 0..39 (all own mid reads done)
        #pragma unroll
        for (int tt = 0; tt < 2; ++tt) {
            f32x4 acc = tt ? acc1 : acc0;
            const int po = w * 32 + tt * 16 + 4 * g;
            float4 S = *(const float4*)(Sm + po);
            float4 T = *(const float4*)(Tm + po);
            uint2 pk;
            pk.x = pk2(bn_act(acc[0], S.x, T.x), bn_act(acc[1], S.y, T.y));
            pk.y = pk2(bn_act(acc[2], S.z, T.z), bn_act(acc[3], S.w, T.w));
            *(uint2*)(my + c * 40 + tt * 16 + 4 * g) = pk;
        }
    }

    __syncthreads();   // barrier 1: all hm slabs visible

    // ---- root col-tile w (waves 0..3): s=0 from x, s=1..8 from hm[v] ----
    if (w < 4) {
        const unsigned short* fb = wsFrag + (WSB_ROOT + w * 9) * 512 + lane * 8;
        f32x4 acc = {0.f,0.f,0.f,0.f};
        {
            const float* rp = xrow + 1152 + (g & 1) * 8;
            float4 xrA = *(const float4*)rp;
            float4 xrB = *(const float4*)(rp + 4);
            bf16x8 bfrag = pack8(xrA, xrB);
            bf16x8 a0 = *(const bf16x8*)fb;
            acc = __builtin_amdgcn_mfma_f32_16x16x32_bf16(a0, bfrag, acc, 0, 0, 0);
        }
        #pragma unroll
        for (int s = 1; s <= 8; ++s) {
            bf16x8 bfrag = *(const bf16x8*)(lds + (s - 1) * 2560 + c * 40 + g * 8);
            bf16x8 a0 = *(const bf16x8*)(fb + s * 512);
            acc = __builtin_amdgcn_mfma_f32_16x16x32_bf16(a0, bfrag, acc, 0, 0, 0);
        }
        const int po = w * 16 + 4 * g;
        float4 S = *(const float4*)(Sr + po);
        float4 T = *(const float4*)(Tr + po);
        uint2 pk;
        pk.x = pk2(bn_act(acc[0], S.x, T.x), bn_act(acc[1], S.y, T.y));
        pk.y = pk2(bn_act(acc[2], S.z, T.z), bn_act(acc[3], S.w, T.w));
        *(uint2*)(hr + c * 72 + w * 16 + 4 * g) = pk;
    }

    __syncthreads();   // barrier 2: hr complete

    // ---- head (wave 0): tasks in rows, samples in cols ----
    if (w == 0) {
        f32x4 acc = {0.f,0.f,0.f,0.f};
        #pragma unroll
        for (int s = 0; s < 2; ++s) {
            bf16x8 bfrag = *(const bf16x8*)(hr + c * 72 + s * 32 + g * 8);
            bf16x8 a0 = *(const bf16x8*)(wsFrag + (WSB_HEAD + s) * 512 + lane * 8);
            acc = __builtin_amdgcn_mfma_f32_16x16x32_bf16(a0, bfrag, acc, 0, 0, 0);
        }
        float* op = out + (size_t)(rowbase + c) * 10 + 4 * g;
        if (g < 2) {
            float2 o1 = {acc[0] + bh[4 * g],     acc[1] + bh[4 * g + 1]};
            float2 o2 = {acc[2] + bh[4 * g + 2], acc[3] + bh[4 * g + 3]};
            *(float2*)op = o1;
            *(float2*)(op + 2) = o2;
        } else if (g == 2) {
            float2 o1 = {acc[0] + bh[8], acc[1] + bh[9]};
            *(float2*)op = o1;
        }
    }
}

extern "C" void kernel_launch(void* const* d_in, const int* in_sizes, int n_in,
                              void* d_out, int out_size, void* d_ws, size_t ws_size,
                              hipStream_t stream) {
    const float* x     = (const float*)d_in[0];
    const float* Wl    = (const float*)d_in[1];
    const float* bl    = (const float*)d_in[2];
    const float* gl    = (const float*)d_in[3];
    const float* betal = (const float*)d_in[4];
    const float* ml    = (const float*)d_in[5];
    const float* vl    = (const float*)d_in[6];
    const float* Wm    = (const float*)d_in[7];
    const float* bm    = (const float*)d_in[8];
    const float* gm    = (const float*)d_in[9];
    const float* betam = (const float*)d_in[10];
    const float* mm    = (const float*)d_in[11];
    const float* vm    = (const float*)d_in[12];
    const float* Wr    = (const float*)d_in[13];
    const float* br    = (const float*)d_in[14];
    const float* gr    = (const float*)d_in[15];
    const float* betar = (const float*)d_in[16];
    const float* mr    = (const float*)d_in[17];
    const float* vr    = (const float*)d_in[18];
    const float* Wh    = (const float*)d_in[19];
    const float* bh    = (const float*)d_in[20];
    float* out = (float*)d_out;

    unsigned short* wsFrag = (unsigned short*)d_ws;
    float* wsST = (float*)((char*)d_ws + WS_ST_BYTE_OFF);

    ontology_prep<<<N_FRAG_BLOCKS + 3, 64, 0, stream>>>(
        Wl, Wm, Wr, Wh, bl, gl, betal, ml, vl, bm, gm, betam, mm, vm,
        br, gr, betar, mr, vr, wsFrag, wsST);

    const int n = in_sizes[0] / 1168;   // 16384
    ontology_mfma<<<n / 16, 512, 0, stream>>>(x, wsFrag, wsST, bh, out);
}

// Round 12
// 32.282 us; speedup vs baseline: 1.0024x; 1.0024x over previous
//
#include <hip/hip_runtime.h>
#include <hip/hip_bf16.h>

typedef __attribute__((ext_vector_type(8))) short bf16x8;
typedef __attribute__((ext_vector_type(4))) float f32x4;

#define EPS 1e-5f
#define K2L 2.8853900817779268f   // 2*log2(e): folds exp(2y) -> exp2(y*K2L)

// ws layout: frag blocks (182 x 1KB bf16) then fp32 ST region
#define N_FRAG_BLOCKS 182
#define WSB_LEAF 0      // 64 blocks: leaf l
#define WSB_MID  64     // 80 blocks: m*10 + tt*5 + s   (K = [hl(128), xm(16), 0(16)])
#define WSB_ROOT 144    // 36 blocks: tt*9 + s
#define WSB_HEAD 180    // 2 blocks: s
#define ST_SL 0
#define ST_TL 1024
#define ST_SM 2048
#define ST_TM 2304
#define ST_SR 2560
#define ST_TR 2624
#define WS_ST_BYTE_OFF (N_FRAG_BLOCKS * 1024)

#define XSW 1192   // u16 stride of staged x rows (2384 B; 596%32=20 -> 2-way max)

__device__ __forceinline__ unsigned short f2bf(float f) {  // RNE float->bf16
    unsigned u = __float_as_uint(f);
    unsigned r = u + 0x7fffu + ((u >> 16) & 1u);
    return (unsigned short)(r >> 16);
}

// packed f32x2 -> bf16x2 (RNE)
__device__ __forceinline__ unsigned pk2(float a, float b) {
    float2 f2; f2.x = a; f2.y = b;
    __hip_bfloat162 h = __float22bfloat162_rn(f2);
    union { __hip_bfloat162 h2; unsigned u; } cv; cv.h2 = h;
    return cv.u;
}

// BN+tanh with pre-folded scale: arg = acc*S' + T' (S',T' carry 2*log2e)
__device__ __forceinline__ float bn_act(float acc, float Sp, float Tp) {
    float e = exp2f(fmaf(acc, Sp, Tp));
    float r = __builtin_amdgcn_rcpf(e + 1.0f);
    return fmaf(-2.0f, r, 1.0f);
}

// ---------------- prep: fragment-ordered bf16 weights + folded BN ----------
// 47 blocks x 256 thr: blocks 0..45 do 4 frag-blocks each; block 46 does ST.
__global__ void ontology_prep(
    const float* __restrict__ Wl, const float* __restrict__ Wm,
    const float* __restrict__ Wr, const float* __restrict__ Wh,
    const float* __restrict__ bl, const float* __restrict__ gl,
    const float* __restrict__ betal, const float* __restrict__ ml,
    const float* __restrict__ vl,
    const float* __restrict__ bm, const float* __restrict__ gm,
    const float* __restrict__ betam, const float* __restrict__ mm,
    const float* __restrict__ vm,
    const float* __restrict__ br, const float* __restrict__ gr,
    const float* __restrict__ betar, const float* __restrict__ mr,
    const float* __restrict__ vr,
    unsigned short* __restrict__ wsFrag, float* __restrict__ wsST)
{
    const int tid = threadIdx.x;
    if (blockIdx.x < 46) {
        const int b = blockIdx.x * 4 + (tid >> 6);
        if (b >= N_FRAG_BLOCKS) return;
        const int t = tid & 63;
        // A'-frag: lane t holds A'[row=t&15][k=(t>>4)*8+i]
        const int row = t & 15, g = t >> 4;
        unsigned short vals[8];
        #pragma unroll
        for (int i = 0; i < 8; ++i) {
            const int k = g * 8 + i;
            float v = 0.f;
            if (b < 64) {                       // leaf l: pair-packed K
                const int l = b;
                if ((l & 1) == 0) { if (k < 16)  v = Wl[l * 256 + k * 16 + row]; }
                else              { if (k >= 16) v = Wl[l * 256 + (k - 16) * 16 + row]; }
            } else if (b < 144) {               // mid: m*10 + tt*5 + s; K=[hl,xm,0]
                const int idx = b - 64, m = idx / 10, rem = idx % 10;
                const int tt = rem / 5, s = rem % 5;
                const int j = s * 32 + k;
                const int krow = (j < 128) ? (16 + j) : ((j < 144) ? (j - 128) : -1);
                if (krow >= 0) v = Wm[m * 4608 + krow * 32 + tt * 16 + row];
            } else if (b < 180) {               // root: tt*9 + s
                const int idx = b - 144, tt = idx / 9, s = idx % 9;
                if (s == 0) { if (k < 16) v = Wr[k * 64 + tt * 16 + row]; }
                else { const int krow = 16 + (s - 1) * 32 + k;
                       v = Wr[krow * 64 + tt * 16 + row]; }
            } else {                            // head
                const int s = b - 180, krow = s * 32 + k;
                if (row < 10) v = Wh[krow * 10 + row];
            }
            vals[i] = f2bf(v);
        }
        #pragma unroll
        for (int i = 0; i < 8; ++i) wsFrag[b * 512 + t * 8 + i] = vals[i];
    } else {
        // ST block (256 thr): leaf 1024, mid 256, root 64 — folded by K2L
        #pragma unroll
        for (int i = 0; i < 4; ++i) {
            const int id = tid + 256 * i;
            const float S = gl[id] * rsqrtf(vl[id] + EPS);
            wsST[ST_SL + id] = S * K2L;
            wsST[ST_TL + id] = ((bl[id] - ml[id]) * S + betal[id]) * K2L;
        }
        {
            const int id = tid;
            const float S = gm[id] * rsqrtf(vm[id] + EPS);
            wsST[ST_SM + id] = S * K2L;
            wsST[ST_TM + id] = ((bm[id] - mm[id]) * S + betam[id]) * K2L;
        }
        if (tid < 64) {
            const int id = tid;
            const float S = gr[id] * rsqrtf(vr[id] + EPS);
            wsST[ST_SR + id] = S * K2L;
            wsST[ST_TR + id] = ((br[id] - mr[id]) * S + betar[id]) * K2L;
        }
    }
}

// ---------------- main fused MFMA kernel: staged-x, in-place LDS -----------
// Block = 512 thr = 8 waves = one 16-sample tile. Phase 0: all threads stream
// the tile's x (74.75 KB) CONTIGUOUSLY into LDS as bf16 (one slab, stride
// 1192 u16). Wave w then owns mid w: leaf pair B-frags read straight from
// the slab, leaf outputs overwrite their own x cols (hl in place), mid reads
// them as K-slots, hm overwrites dead hl cols, root (waves 0..3) reads hm
// slabs, hr goes to another dead region, head reads hr. 3 barriers.
__global__ __launch_bounds__(512, 8) void ontology_mfma(
    const float* __restrict__ x,
    const unsigned short* __restrict__ wsFrag,
    const float* __restrict__ wsST,
    const float* __restrict__ bh,
    float* __restrict__ out)
{
    __shared__ __align__(16) unsigned short xs[16 * XSW];   // 38144 B

    const int tid  = threadIdx.x;
    const int w    = tid >> 6;
    const int lane = tid & 63;
    const int c    = lane & 15;       // sample within tile
    const int g    = lane >> 4;       // k/feat group
    const int rowbase = blockIdx.x * 16;

    const float* Sl = wsST + ST_SL; const float* Tl = wsST + ST_TL;
    const float* Sm = wsST + ST_SM; const float* Tm = wsST + ST_TM;
    const float* Sr = wsST + ST_SR; const float* Tr = wsST + ST_TR;

    // ---- phase 0: contiguous stage of x tile -> bf16 slab ----
    {
        const float4* xt = (const float4*)(x + (size_t)rowbase * 1168);
        #pragma unroll
        for (int k = 0; k < 9; ++k) {
            const int idx4 = k * 512 + tid;          // 0..4607 < 4672
            float4 v = xt[idx4];
            const int f = idx4 * 4;
            const int row = f / 1168;
            const int col = f - row * 1168;
            uint2 p; p.x = pk2(v.x, v.y); p.y = pk2(v.z, v.w);
            *(uint2*)(xs + row * XSW + col) = p;
        }
        if (tid < 64) {                               // tail: idx4 4608..4671
            const int idx4 = 4608 + tid;
            float4 v = xt[idx4];
            const int f = idx4 * 4;
            const int row = f / 1168;
            const int col = f - row * 1168;
            uint2 p; p.x = pk2(v.x, v.y); p.y = pk2(v.z, v.w);
            *(uint2*)(xs + row * XSW + col) = p;
        }
        if (tid < 64) {                               // zero cols 1168..1184
            const int row = tid >> 2, seg = tid & 3;
            uint2 z; z.x = 0u; z.y = 0u;
            *(uint2*)(xs + row * XSW + 1168 + seg * 4) = z;
        }
    }
    __syncthreads();   // B1: slab staged

    // ---- wave w: 8 leaves of mid w (B-frags from slab, outputs in place) ---
    const int colbase = w * 128;
    #pragma unroll
    for (int p = 0; p < 4; ++p) {
        bf16x8 bfrag = *(const bf16x8*)(xs + c * XSW + colbase + p * 32 + g * 8);
        #pragma unroll
        for (int e = 0; e < 2; ++e) {
            const int l = 2 * p + e, leaf = w * 8 + l;
            bf16x8 afrag = *(const bf16x8*)(wsFrag + (WSB_LEAF + leaf) * 512 + lane * 8);
            f32x4 zz = {0.f,0.f,0.f,0.f};
            f32x4 acc = __builtin_amdgcn_mfma_f32_16x16x32_bf16(afrag, bfrag, zz, 0, 0, 0);
            const int po = leaf * 16 + 4 * g;
            float4 S = *(const float4*)(Sl + po);
            float4 T = *(const float4*)(Tl + po);
            uint2 pk;
            pk.x = pk2(bn_act(acc[0], S.x, T.x), bn_act(acc[1], S.y, T.y));
            pk.y = pk2(bn_act(acc[2], S.z, T.z), bn_act(acc[3], S.w, T.w));
            // hl in place over the consumed x cols of this leaf
            *(uint2*)(xs + c * XSW + colbase + l * 16 + 4 * g) = pk;
        }
    }

    // ---- mid w: K = [hl(128) at colbase, xm(16)+spill at 1024+w*16] --------
    {
        f32x4 acc0 = {0.f,0.f,0.f,0.f};
        f32x4 acc1 = {0.f,0.f,0.f,0.f};
        const unsigned short* fb = wsFrag + (WSB_MID + w * 10) * 512 + lane * 8;
        #pragma unroll
        for (int s = 0; s < 5; ++s) {
            const int cc = (s < 4) ? (colbase + s * 32) : (1024 + w * 16);
            bf16x8 bfrag = *(const bf16x8*)(xs + c * XSW + cc + g * 8);
            bf16x8 a0 = *(const bf16x8*)(fb + s * 512);
            bf16x8 a1 = *(const bf16x8*)(fb + (5 + s) * 512);
            acc0 = __builtin_amdgcn_mfma_f32_16x16x32_bf16(a0, bfrag, acc0, 0, 0, 0);
            acc1 = __builtin_amdgcn_mfma_f32_16x16x32_bf16(a1, bfrag, acc1, 0, 0, 0);
        }
        #pragma unroll
        for (int tt = 0; tt < 2; ++tt) {
            f32x4 acc = tt ? acc1 : acc0;
            const int po = w * 32 + tt * 16 + 4 * g;
            float4 S = *(const float4*)(Sm + po);
            float4 T = *(const float4*)(Tm + po);
            uint2 pk;
            pk.x = pk2(bn_act(acc[0], S.x, T.x), bn_act(acc[1], S.y, T.y));
            pk.y = pk2(bn_act(acc[2], S.z, T.z), bn_act(acc[3], S.w, T.w));
            // hm[w] over dead hl cols: colbase + tt*16 + 4g  (feats w*32+...)
            *(uint2*)(xs + c * XSW + colbase + tt * 16 + 4 * g) = pk;
        }
    }
    __syncthreads();   // B2: all hm slabs in place

    // ---- root col-tile w (waves 0..3): s=0 from x cols 1152, s=1..8 hm -----
    if (w < 4) {
        const unsigned short* fb = wsFrag + (WSB_ROOT + w * 9) * 512 + lane * 8;
        f32x4 acc = {0.f,0.f,0.f,0.f};
        {
            bf16x8 bfrag = *(const bf16x8*)(xs + c * XSW + 1152 + g * 8);
            bf16x8 a0 = *(const bf16x8*)fb;
            acc = __builtin_amdgcn_mfma_f32_16x16x32_bf16(a0, bfrag, acc, 0, 0, 0);
        }
        #pragma unroll
        for (int s = 1; s <= 8; ++s) {
            bf16x8 bfrag = *(const bf16x8*)(xs + c * XSW + (s - 1) * 128 + g * 8);
            bf16x8 a0 = *(const bf16x8*)(fb + s * 512);
            acc = __builtin_amdgcn_mfma_f32_16x16x32_bf16(a0, bfrag, acc, 0, 0, 0);
        }
        const int po = w * 16 + 4 * g;
        float4 S = *(const float4*)(Sr + po);
        float4 T = *(const float4*)(Tr + po);
        uint2 pk;
        pk.x = pk2(bn_act(acc[0], S.x, T.x), bn_act(acc[1], S.y, T.y));
        pk.y = pk2(bn_act(acc[2], S.z, T.z), bn_act(acc[3], S.w, T.w));
        // hr at cols 32..96 (dead hl region of mid 0, disjoint from hm reads)
        *(uint2*)(xs + c * XSW + 32 + w * 16 + 4 * g) = pk;
    }
    __syncthreads();   // B3: hr complete

    // ---- head (wave 0): tasks in rows, samples in cols ----
    if (w == 0) {
        f32x4 acc = {0.f,0.f,0.f,0.f};
        #pragma unroll
        for (int s = 0; s < 2; ++s) {
            bf16x8 bfrag = *(const bf16x8*)(xs + c * XSW + 32 + s * 32 + g * 8);
            bf16x8 a0 = *(const bf16x8*)(wsFrag + (WSB_HEAD + s) * 512 + lane * 8);
            acc = __builtin_amdgcn_mfma_f32_16x16x32_bf16(a0, bfrag, acc, 0, 0, 0);
        }
        float* op = out + (size_t)(rowbase + c) * 10 + 4 * g;
        if (g < 2) {
            float2 o1 = {acc[0] + bh[4 * g],     acc[1] + bh[4 * g + 1]};
            float2 o2 = {acc[2] + bh[4 * g + 2], acc[3] + bh[4 * g + 3]};
            *(float2*)op = o1;
            *(float2*)(op + 2) = o2;
        } else if (g == 2) {
            float2 o1 = {acc[0] + bh[8], acc[1] + bh[9]};
            *(float2*)op = o1;
        }
    }
}

extern "C" void kernel_launch(void* const* d_in, const int* in_sizes, int n_in,
                              void* d_out, int out_size, void* d_ws, size_t ws_size,
                              hipStream_t stream) {
    const float* x     = (const float*)d_in[0];
    const float* Wl    = (const float*)d_in[1];
    const float* bl    = (const float*)d_in[2];
    const float* gl    = (const float*)d_in[3];
    const float* betal = (const float*)d_in[4];
    const float* ml    = (const float*)d_in[5];
    const float* vl    = (const float*)d_in[6];
    const float* Wm    = (const float*)d_in[7];
    const float* bm    = (const float*)d_in[8];
    const float* gm    = (const float*)d_in[9];
    const float* betam = (const float*)d_in[10];
    const float* mm    = (const float*)d_in[11];
    const float* vm    = (const float*)d_in[12];
    const float* Wr    = (const float*)d_in[13];
    const float* br    = (const float*)d_in[14];
    const float* gr    = (const float*)d_in[15];
    const float* betar = (const float*)d_in[16];
    const float* mr    = (const float*)d_in[17];
    const float* vr    = (const float*)d_in[18];
    const float* Wh    = (const float*)d_in[19];
    const float* bh    = (const float*)d_in[20];
    float* out = (float*)d_out;

    unsigned short* wsFrag = (unsigned short*)d_ws;
    float* wsST = (float*)((char*)d_ws + WS_ST_BYTE_OFF);

    ontology_prep<<<47, 256, 0, stream>>>(
        Wl, Wm, Wr, Wh, bl, gl, betal, ml, vl, bm, gm, betam, mm, vm,
        br, gr, betar, mr, vr, wsFrag, wsST);

    const int n = in_sizes[0] / 1168;   // 16384
    ontology_mfma<<<n / 16, 512, 0, stream>>>(x, wsFrag, wsST, bh, out);
}

// Round 13
// 31.946 us; speedup vs baseline: 1.0129x; 1.0105x over previous
//
#include <hip/hip_runtime.h>
#include <hip/hip_bf16.h>

typedef __attribute__((ext_vector_type(8))) short bf16x8;
typedef __attribute__((ext_vector_type(4))) float f32x4;

#define EPS 1e-5f
#define K2L 2.8853900817779268f   // 2*log2(e): folds exp(2y) -> exp2(y*K2L)

// ws layout: frag blocks (182 x 1KB bf16) then fp32 ST region
#define N_FRAG_BLOCKS 182
#define WSB_LEAF 0      // 64 blocks: leaf l
#define WSB_MID  64     // 80 blocks: m*10 + tt*5 + s   (K = [hl(128), xm(16), 0(16)])
#define WSB_ROOT 144    // 36 blocks: tt*9 + s
#define WSB_HEAD 180    // 2 blocks: s
#define ST_SL 0
#define ST_TL 1024
#define ST_SM 2048
#define ST_TM 2304
#define ST_SR 2560
#define ST_TR 2624
#define WS_ST_BYTE_OFF (N_FRAG_BLOCKS * 1024)

#define XSW 1192   // u16 stride of staged x rows (2384 B; 2-way bank alias max)

__device__ __forceinline__ unsigned short f2bf(float f) {  // RNE float->bf16
    unsigned u = __float_as_uint(f);
    unsigned r = u + 0x7fffu + ((u >> 16) & 1u);
    return (unsigned short)(r >> 16);
}

// packed f32x2 -> bf16x2 (RNE)
__device__ __forceinline__ unsigned pk2(float a, float b) {
    float2 f2; f2.x = a; f2.y = b;
    __hip_bfloat162 h = __float22bfloat162_rn(f2);
    union { __hip_bfloat162 h2; unsigned u; } cv; cv.h2 = h;
    return cv.u;
}

// BN+tanh with pre-folded scale: arg = acc*S' + T' (S',T' carry 2*log2e)
__device__ __forceinline__ float bn_act(float acc, float Sp, float Tp) {
    float e = exp2f(fmaf(acc, Sp, Tp));
    float r = __builtin_amdgcn_rcpf(e + 1.0f);
    return fmaf(-2.0f, r, 1.0f);
}

// ---------------- prep: fragment-ordered bf16 weights + folded BN ----------
__global__ void ontology_prep(
    const float* __restrict__ Wl, const float* __restrict__ Wm,
    const float* __restrict__ Wr, const float* __restrict__ Wh,
    const float* __restrict__ bl, const float* __restrict__ gl,
    const float* __restrict__ betal, const float* __restrict__ ml,
    const float* __restrict__ vl,
    const float* __restrict__ bm, const float* __restrict__ gm,
    const float* __restrict__ betam, const float* __restrict__ mm,
    const float* __restrict__ vm,
    const float* __restrict__ br, const float* __restrict__ gr,
    const float* __restrict__ betar, const float* __restrict__ mr,
    const float* __restrict__ vr,
    unsigned short* __restrict__ wsFrag, float* __restrict__ wsST)
{
    const int tid = threadIdx.x;
    if (blockIdx.x < 46) {
        const int b = blockIdx.x * 4 + (tid >> 6);
        if (b >= N_FRAG_BLOCKS) return;
        const int t = tid & 63;
        const int row = t & 15, g = t >> 4;
        unsigned short vals[8];
        #pragma unroll
        for (int i = 0; i < 8; ++i) {
            const int k = g * 8 + i;
            float v = 0.f;
            if (b < 64) {                       // leaf l: pair-packed K
                const int l = b;
                if ((l & 1) == 0) { if (k < 16)  v = Wl[l * 256 + k * 16 + row]; }
                else              { if (k >= 16) v = Wl[l * 256 + (k - 16) * 16 + row]; }
            } else if (b < 144) {               // mid: m*10 + tt*5 + s; K=[hl,xm,0]
                const int idx = b - 64, m = idx / 10, rem = idx % 10;
                const int tt = rem / 5, s = rem % 5;
                const int j = s * 32 + k;
                const int krow = (j < 128) ? (16 + j) : ((j < 144) ? (j - 128) : -1);
                if (krow >= 0) v = Wm[m * 4608 + krow * 32 + tt * 16 + row];
            } else if (b < 180) {               // root: tt*9 + s
                const int idx = b - 144, tt = idx / 9, s = idx % 9;
                if (s == 0) { if (k < 16) v = Wr[k * 64 + tt * 16 + row]; }
                else { const int krow = 16 + (s - 1) * 32 + k;
                       v = Wr[krow * 64 + tt * 16 + row]; }
            } else {                            // head
                const int s = b - 180, krow = s * 32 + k;
                if (row < 10) v = Wh[krow * 10 + row];
            }
            vals[i] = f2bf(v);
        }
        #pragma unroll
        for (int i = 0; i < 8; ++i) wsFrag[b * 512 + t * 8 + i] = vals[i];
    } else {
        #pragma unroll
        for (int i = 0; i < 4; ++i) {
            const int id = tid + 256 * i;
            const float S = gl[id] * rsqrtf(vl[id] + EPS);
            wsST[ST_SL + id] = S * K2L;
            wsST[ST_TL + id] = ((bl[id] - ml[id]) * S + betal[id]) * K2L;
        }
        {
            const int id = tid;
            const float S = gm[id] * rsqrtf(vm[id] + EPS);
            wsST[ST_SM + id] = S * K2L;
            wsST[ST_TM + id] = ((bm[id] - mm[id]) * S + betam[id]) * K2L;
        }
        if (tid < 64) {
            const int id = tid;
            const float S = gr[id] * rsqrtf(vr[id] + EPS);
            wsST[ST_SR + id] = S * K2L;
            wsST[ST_TR + id] = ((br[id] - mr[id]) * S + betar[id]) * K2L;
        }
    }
}

// ---------------- main: 32-sample tiles, 2x A-frag reuse -------------------
// Block = 512 thr = 8 waves = one 32-sample tile (two 16-sample halves).
// Phase 0: contiguous stage of 146 KB fp32 x -> 73 KB bf16 slab.
// Wave w owns mid w for BOTH halves: each afrag loaded once, 2 MFMAs.
// In-place LDS: hl over x cols, hm over dead hl, hr in dead region.
// 512 blocks = 2/CU (76.3 KB LDS) = 16 waves/CU. 3 barriers.
__global__ __launch_bounds__(512, 4) void ontology_mfma(
    const float* __restrict__ x,
    const unsigned short* __restrict__ wsFrag,
    const float* __restrict__ wsST,
    const float* __restrict__ bh,
    float* __restrict__ out)
{
    __shared__ __align__(16) unsigned short xs[32 * XSW];   // 76288 B

    const int tid  = threadIdx.x;
    const int w    = tid >> 6;
    const int lane = tid & 63;
    const int c    = lane & 15;       // sample within half-tile
    const int g    = lane >> 4;       // k/feat group
    const int rowbase = blockIdx.x * 32;

    const float* Sl = wsST + ST_SL; const float* Tl = wsST + ST_TL;
    const float* Sm = wsST + ST_SM; const float* Tm = wsST + ST_TM;
    const float* Sr = wsST + ST_SR; const float* Tr = wsST + ST_TR;

    // ---- phase 0: contiguous stage of x tile -> bf16 slab ----
    {
        const float4* xt = (const float4*)(x + (size_t)rowbase * 1168);
        #pragma unroll
        for (int k = 0; k < 18; ++k) {
            const int idx4 = k * 512 + tid;          // 0..9215
            float4 v = xt[idx4];
            const int f = idx4 * 4;
            const int row = f / 1168;
            const int col = f - row * 1168;
            uint2 p; p.x = pk2(v.x, v.y); p.y = pk2(v.z, v.w);
            *(uint2*)(xs + row * XSW + col) = p;
        }
        if (tid < 128) {                              // tail: idx4 9216..9343
            const int idx4 = 9216 + tid;
            float4 v = xt[idx4];
            const int f = idx4 * 4;
            const int row = f / 1168;
            const int col = f - row * 1168;
            uint2 p; p.x = pk2(v.x, v.y); p.y = pk2(v.z, v.w);
            *(uint2*)(xs + row * XSW + col) = p;
        }
        if (tid < 128) {                              // zero cols 1168..1184
            const int row = tid >> 2, seg = tid & 3;
            uint2 z; z.x = 0u; z.y = 0u;
            *(uint2*)(xs + row * XSW + 1168 + seg * 4) = z;
        }
    }
    __syncthreads();   // B1: slab staged

    const int r0 = c;            // half-0 row
    const int r1 = 16 + c;       // half-1 row
    const int colbase = w * 128;

    // ---- wave w: 8 leaves of mid w, afrag shared across both halves -------
    #pragma unroll
    for (int p = 0; p < 4; ++p) {
        bf16x8 bf0 = *(const bf16x8*)(xs + r0 * XSW + colbase + p * 32 + g * 8);
        bf16x8 bf1 = *(const bf16x8*)(xs + r1 * XSW + colbase + p * 32 + g * 8);
        #pragma unroll
        for (int e = 0; e < 2; ++e) {
            const int l = 2 * p + e, leaf = w * 8 + l;
            bf16x8 afrag = *(const bf16x8*)(wsFrag + (WSB_LEAF + leaf) * 512 + lane * 8);
            const int po = leaf * 16 + 4 * g;
            float4 S = *(const float4*)(Sl + po);
            float4 T = *(const float4*)(Tl + po);
            f32x4 zz = {0.f,0.f,0.f,0.f};
            f32x4 a0 = __builtin_amdgcn_mfma_f32_16x16x32_bf16(afrag, bf0, zz, 0, 0, 0);
            f32x4 a1 = __builtin_amdgcn_mfma_f32_16x16x32_bf16(afrag, bf1, zz, 0, 0, 0);
            uint2 k0, k1;
            k0.x = pk2(bn_act(a0[0], S.x, T.x), bn_act(a0[1], S.y, T.y));
            k0.y = pk2(bn_act(a0[2], S.z, T.z), bn_act(a0[3], S.w, T.w));
            k1.x = pk2(bn_act(a1[0], S.x, T.x), bn_act(a1[1], S.y, T.y));
            k1.y = pk2(bn_act(a1[2], S.z, T.z), bn_act(a1[3], S.w, T.w));
            *(uint2*)(xs + r0 * XSW + colbase + l * 16 + 4 * g) = k0;
            *(uint2*)(xs + r1 * XSW + colbase + l * 16 + 4 * g) = k1;
        }
    }

    // ---- mid w, both halves; K = [hl(128), xm(16)+pad] --------------------
    {
        f32x4 c00 = {0.f,0.f,0.f,0.f}, c01 = {0.f,0.f,0.f,0.f};
        f32x4 c10 = {0.f,0.f,0.f,0.f}, c11 = {0.f,0.f,0.f,0.f};
        const unsigned short* fb = wsFrag + (WSB_MID + w * 10) * 512 + lane * 8;
        #pragma unroll
        for (int s = 0; s < 5; ++s) {
            const int cc = (s < 4) ? (colbase + s * 32) : (1024 + w * 16);
            bf16x8 bf0 = *(const bf16x8*)(xs + r0 * XSW + cc + g * 8);
            bf16x8 bf1 = *(const bf16x8*)(xs + r1 * XSW + cc + g * 8);
            bf16x8 a0 = *(const bf16x8*)(fb + s * 512);
            bf16x8 a1 = *(const bf16x8*)(fb + (5 + s) * 512);
            c00 = __builtin_amdgcn_mfma_f32_16x16x32_bf16(a0, bf0, c00, 0, 0, 0);
            c01 = __builtin_amdgcn_mfma_f32_16x16x32_bf16(a1, bf0, c01, 0, 0, 0);
            c10 = __builtin_amdgcn_mfma_f32_16x16x32_bf16(a0, bf1, c10, 0, 0, 0);
            c11 = __builtin_amdgcn_mfma_f32_16x16x32_bf16(a1, bf1, c11, 0, 0, 0);
        }
        #pragma unroll
        for (int tt = 0; tt < 2; ++tt) {
            const int po = w * 32 + tt * 16 + 4 * g;
            float4 S = *(const float4*)(Sm + po);
            float4 T = *(const float4*)(Tm + po);
            f32x4 a0 = tt ? c01 : c00;
            f32x4 a1 = tt ? c11 : c10;
            uint2 k0, k1;
            k0.x = pk2(bn_act(a0[0], S.x, T.x), bn_act(a0[1], S.y, T.y));
            k0.y = pk2(bn_act(a0[2], S.z, T.z), bn_act(a0[3], S.w, T.w));
            k1.x = pk2(bn_act(a1[0], S.x, T.x), bn_act(a1[1], S.y, T.y));
            k1.y = pk2(bn_act(a1[2], S.z, T.z), bn_act(a1[3], S.w, T.w));
            *(uint2*)(xs + r0 * XSW + colbase + tt * 16 + 4 * g) = k0;
            *(uint2*)(xs + r1 * XSW + colbase + tt * 16 + 4 * g) = k1;
        }
    }
    __syncthreads();   // B2: all hm slabs in place

    // ---- root col-tile w (waves 0..3), both halves ------------------------
    if (w < 4) {
        const unsigned short* fb = wsFrag + (WSB_ROOT + w * 9) * 512 + lane * 8;
        f32x4 a0 = {0.f,0.f,0.f,0.f}, a1 = {0.f,0.f,0.f,0.f};
        {
            bf16x8 bf0 = *(const bf16x8*)(xs + r0 * XSW + 1152 + g * 8);
            bf16x8 bf1 = *(const bf16x8*)(xs + r1 * XSW + 1152 + g * 8);
            bf16x8 af = *(const bf16x8*)fb;
            a0 = __builtin_amdgcn_mfma_f32_16x16x32_bf16(af, bf0, a0, 0, 0, 0);
            a1 = __builtin_amdgcn_mfma_f32_16x16x32_bf16(af, bf1, a1, 0, 0, 0);
        }
        #pragma unroll
        for (int s = 1; s <= 8; ++s) {
            bf16x8 bf0 = *(const bf16x8*)(xs + r0 * XSW + (s - 1) * 128 + g * 8);
            bf16x8 bf1 = *(const bf16x8*)(xs + r1 * XSW + (s - 1) * 128 + g * 8);
            bf16x8 af = *(const bf16x8*)(fb + s * 512);
            a0 = __builtin_amdgcn_mfma_f32_16x16x32_bf16(af, bf0, a0, 0, 0, 0);
            a1 = __builtin_amdgcn_mfma_f32_16x16x32_bf16(af, bf1, a1, 0, 0, 0);
        }
        const int po = w * 16 + 4 * g;
        float4 S = *(const float4*)(Sr + po);
        float4 T = *(const float4*)(Tr + po);
        uint2 k0, k1;
        k0.x = pk2(bn_act(a0[0], S.x, T.x), bn_act(a0[1], S.y, T.y));
        k0.y = pk2(bn_act(a0[2], S.z, T.z), bn_act(a0[3], S.w, T.w));
        k1.x = pk2(bn_act(a1[0], S.x, T.x), bn_act(a1[1], S.y, T.y));
        k1.y = pk2(bn_act(a1[2], S.z, T.z), bn_act(a1[3], S.w, T.w));
        // hr at cols 32..96 (dead hl region of mid 0)
        *(uint2*)(xs + r0 * XSW + 32 + w * 16 + 4 * g) = k0;
        *(uint2*)(xs + r1 * XSW + 32 + w * 16 + 4 * g) = k1;
    }
    __syncthreads();   // B3: hr complete

    // ---- head: wave 0 -> half 0, wave 4 -> half 1 -------------------------
    if (w == 0 || w == 4) {
        const int r = (w >> 2) * 16 + c;
        f32x4 acc = {0.f,0.f,0.f,0.f};
        #pragma unroll
        for (int s = 0; s < 2; ++s) {
            bf16x8 bfrag = *(const bf16x8*)(xs + r * XSW + 32 + s * 32 + g * 8);
            bf16x8 a0 = *(const bf16x8*)(wsFrag + (WSB_HEAD + s) * 512 + lane * 8);
            acc = __builtin_amdgcn_mfma_f32_16x16x32_bf16(a0, bfrag, acc, 0, 0, 0);
        }
        float* op = out + (size_t)(rowbase + r) * 10 + 4 * g;
        if (g < 2) {
            float2 o1 = {acc[0] + bh[4 * g],     acc[1] + bh[4 * g + 1]};
            float2 o2 = {acc[2] + bh[4 * g + 2], acc[3] + bh[4 * g + 3]};
            *(float2*)op = o1;
            *(float2*)(op + 2) = o2;
        } else if (g == 2) {
            float2 o1 = {acc[0] + bh[8], acc[1] + bh[9]};
            *(float2*)op = o1;
        }
    }
}

extern "C" void kernel_launch(void* const* d_in, const int* in_sizes, int n_in,
                              void* d_out, int out_size, void* d_ws, size_t ws_size,
                              hipStream_t stream) {
    const float* x     = (const float*)d_in[0];
    const float* Wl    = (const float*)d_in[1];
    const float* bl    = (const float*)d_in[2];
    const float* gl    = (const float*)d_in[3];
    const float* betal = (const float*)d_in[4];
    const float* ml    = (const float*)d_in[5];
    const float* vl    = (const float*)d_in[6];
    const float* Wm    = (const float*)d_in[7];
    const float* bm    = (const float*)d_in[8];
    const float* gm    = (const float*)d_in[9];
    const float* betam = (const float*)d_in[10];
    const float* mm    = (const float*)d_in[11];
    const float* vm    = (const float*)d_in[12];
    const float* Wr    = (const float*)d_in[13];
    const float* br    = (const float*)d_in[14];
    const float* gr    = (const float*)d_in[15];
    const float* betar = (const float*)d_in[16];
    const float* mr    = (const float*)d_in[17];
    const float* vr    = (const float*)d_in[18];
    const float* Wh    = (const float*)d_in[19];
    const float* bh    = (const float*)d_in[20];
    float* out = (float*)d_out;

    unsigned short* wsFrag = (unsigned short*)d_ws;
    float* wsST = (float*)((char*)d_ws + WS_ST_BYTE_OFF);

    ontology_prep<<<47, 256, 0, stream>>>(
        Wl, Wm, Wr, Wh, bl, gl, betal, ml, vl, bm, gm, betam, mm, vm,
        br, gr, betar, mr, vr, wsFrag, wsST);

    const int n = in_sizes[0] / 1168;   // 16384
    ontology_mfma<<<n / 32, 512, 0, stream>>>(x, wsFrag, wsST, bh, out);
}

// Round 14
// 31.694 us; speedup vs baseline: 1.0210x; 1.0079x over previous
//
#include <hip/hip_runtime.h>
#include <hip/hip_bf16.h>

typedef __attribute__((ext_vector_type(8))) short bf16x8;
typedef __attribute__((ext_vector_type(4))) float f32x4;

#define EPS 1e-5f
#define K2L 2.8853900817779268f   // 2*log2(e): folds exp(2y) -> exp2(y*K2L)

// ws layout: frag blocks (182 x 1KB bf16) then fp32 ST region
#define N_FRAG_BLOCKS 182
#define WSB_LEAF 0      // 64 blocks: leaf l
#define WSB_MID  64     // 80 blocks: m*10 + tt*5 + s   (K = [hl(128), xm(16), 0(16)])
#define WSB_ROOT 144    // 36 blocks: tt*9 + s
#define WSB_HEAD 180    // 2 blocks: s
#define ST_SL 0
#define ST_TL 1024
#define ST_SM 2048
#define ST_TM 2304
#define ST_SR 2560
#define ST_TR 2624
#define WS_ST_BYTE_OFF (N_FRAG_BLOCKS * 1024)

#define XSW 1192   // u16 stride of staged x rows (2384 B; 2-way bank alias max)

__device__ __forceinline__ unsigned short f2bf(float f) {  // RNE float->bf16
    unsigned u = __float_as_uint(f);
    unsigned r = u + 0x7fffu + ((u >> 16) & 1u);
    return (unsigned short)(r >> 16);
}

// packed f32x2 -> bf16x2 (RNE)
__device__ __forceinline__ unsigned pk2(float a, float b) {
    float2 f2; f2.x = a; f2.y = b;
    __hip_bfloat162 h = __float22bfloat162_rn(f2);
    union { __hip_bfloat162 h2; unsigned u; } cv; cv.h2 = h;
    return cv.u;
}

// BN+tanh with pre-folded scale: arg = acc*S' + T' (S',T' carry 2*log2e)
__device__ __forceinline__ float bn_act(float acc, float Sp, float Tp) {
    float e = exp2f(fmaf(acc, Sp, Tp));
    float r = __builtin_amdgcn_rcpf(e + 1.0f);
    return fmaf(-2.0f, r, 1.0f);
}

// ---------------- prep: fragment-ordered bf16 weights + folded BN ----------
__global__ void ontology_prep(
    const float* __restrict__ Wl, const float* __restrict__ Wm,
    const float* __restrict__ Wr, const float* __restrict__ Wh,
    const float* __restrict__ bl, const float* __restrict__ gl,
    const float* __restrict__ betal, const float* __restrict__ ml,
    const float* __restrict__ vl,
    const float* __restrict__ bm, const float* __restrict__ gm,
    const float* __restrict__ betam, const float* __restrict__ mm,
    const float* __restrict__ vm,
    const float* __restrict__ br, const float* __restrict__ gr,
    const float* __restrict__ betar, const float* __restrict__ mr,
    const float* __restrict__ vr,
    unsigned short* __restrict__ wsFrag, float* __restrict__ wsST)
{
    const int tid = threadIdx.x;
    if (blockIdx.x < 46) {
        const int b = blockIdx.x * 4 + (tid >> 6);
        if (b >= N_FRAG_BLOCKS) return;
        const int t = tid & 63;
        const int row = t & 15, g = t >> 4;
        unsigned short vals[8];
        #pragma unroll
        for (int i = 0; i < 8; ++i) {
            const int k = g * 8 + i;
            float v = 0.f;
            if (b < 64) {                       // leaf l: pair-packed K
                const int l = b;
                if ((l & 1) == 0) { if (k < 16)  v = Wl[l * 256 + k * 16 + row]; }
                else              { if (k >= 16) v = Wl[l * 256 + (k - 16) * 16 + row]; }
            } else if (b < 144) {               // mid: m*10 + tt*5 + s; K=[hl,xm,0]
                const int idx = b - 64, m = idx / 10, rem = idx % 10;
                const int tt = rem / 5, s = rem % 5;
                const int j = s * 32 + k;
                const int krow = (j < 128) ? (16 + j) : ((j < 144) ? (j - 128) : -1);
                if (krow >= 0) v = Wm[m * 4608 + krow * 32 + tt * 16 + row];
            } else if (b < 180) {               // root: tt*9 + s
                const int idx = b - 144, tt = idx / 9, s = idx % 9;
                if (s == 0) { if (k < 16) v = Wr[k * 64 + tt * 16 + row]; }
                else { const int krow = 16 + (s - 1) * 32 + k;
                       v = Wr[krow * 64 + tt * 16 + row]; }
            } else {                            // head
                const int s = b - 180, krow = s * 32 + k;
                if (row < 10) v = Wh[krow * 10 + row];
            }
            vals[i] = f2bf(v);
        }
        #pragma unroll
        for (int i = 0; i < 8; ++i) wsFrag[b * 512 + t * 8 + i] = vals[i];
    } else {
        #pragma unroll
        for (int i = 0; i < 4; ++i) {
            const int id = tid + 256 * i;
            const float S = gl[id] * rsqrtf(vl[id] + EPS);
            wsST[ST_SL + id] = S * K2L;
            wsST[ST_TL + id] = ((bl[id] - ml[id]) * S + betal[id]) * K2L;
        }
        {
            const int id = tid;
            const float S = gm[id] * rsqrtf(vm[id] + EPS);
            wsST[ST_SM + id] = S * K2L;
            wsST[ST_TM + id] = ((bm[id] - mm[id]) * S + betam[id]) * K2L;
        }
        if (tid < 64) {
            const int id = tid;
            const float S = gr[id] * rsqrtf(vr[id] + EPS);
            wsST[ST_SR + id] = S * K2L;
            wsST[ST_TR + id] = ((br[id] - mr[id]) * S + betar[id]) * K2L;
        }
    }
}

// ---------------- main fused MFMA kernel: batched-issue staged-x -----------
// Block = 512 thr = 8 waves = one 16-sample tile. Phase 0: thread = (row,
// lane-in-row); loads issued in batches of 5 float4 (5 KB in flight per
// wave-thread-group -> 160 KB/CU) so the x stream saturates the memory
// system. All compute after B1 identical to R12 (verified): in-place LDS,
// wave w owns mid w, root waves 0..3, head wave 0. 3 barriers.
__global__ __launch_bounds__(512, 8) void ontology_mfma(
    const float* __restrict__ x,
    const unsigned short* __restrict__ wsFrag,
    const float* __restrict__ wsST,
    const float* __restrict__ bh,
    float* __restrict__ out)
{
    __shared__ __align__(16) unsigned short xs[16 * XSW];   // 38144 B

    const int tid  = threadIdx.x;
    const int w    = tid >> 6;
    const int lane = tid & 63;
    const int c    = lane & 15;       // sample within tile
    const int g    = lane >> 4;       // k/feat group
    const int rowbase = blockIdx.x * 16;

    const float* Sl = wsST + ST_SL; const float* Tl = wsST + ST_TL;
    const float* Sm = wsST + ST_SM; const float* Tm = wsST + ST_TM;
    const float* Sr = wsST + ST_SR; const float* Tr = wsST + ST_TR;

    // ---- phase 0: batched contiguous stage of x tile -> bf16 slab ----
    // row = tid>>5 (16 rows), j = tid&31. Row = 292 float4; thread covers
    // j, j+32, ..., j+288 (last only for j<4). Batch A: i=0..4, B: i=5..9.
    {
        const int srow = tid >> 5;
        const int j    = tid & 31;
        const float4* xr4 = (const float4*)(x + (size_t)(rowbase + srow) * 1168);
        unsigned short* xsrow = xs + srow * XSW;

        float4 v0, v1, v2, v3, v4;
        // ---- batch A: issue 5 loads, then convert+store ----
        v0 = xr4[j];       v1 = xr4[j + 32];  v2 = xr4[j + 64];
        v3 = xr4[j + 96];  v4 = xr4[j + 128];
        {
            uint2 p;
            p.x = pk2(v0.x, v0.y); p.y = pk2(v0.z, v0.w); *(uint2*)(xsrow + (j      ) * 4) = p;
            p.x = pk2(v1.x, v1.y); p.y = pk2(v1.z, v1.w); *(uint2*)(xsrow + (j +  32) * 4) = p;
            p.x = pk2(v2.x, v2.y); p.y = pk2(v2.z, v2.w); *(uint2*)(xsrow + (j +  64) * 4) = p;
            p.x = pk2(v3.x, v3.y); p.y = pk2(v3.z, v3.w); *(uint2*)(xsrow + (j +  96) * 4) = p;
            p.x = pk2(v4.x, v4.y); p.y = pk2(v4.z, v4.w); *(uint2*)(xsrow + (j + 128) * 4) = p;
        }
        // ---- batch B: 4 full + 1 partial ----
        v0 = xr4[j + 160]; v1 = xr4[j + 192]; v2 = xr4[j + 224]; v3 = xr4[j + 256];
        const bool has9 = (j < 4);
        if (has9) v4 = xr4[j + 288];
        {
            uint2 p;
            p.x = pk2(v0.x, v0.y); p.y = pk2(v0.z, v0.w); *(uint2*)(xsrow + (j + 160) * 4) = p;
            p.x = pk2(v1.x, v1.y); p.y = pk2(v1.z, v1.w); *(uint2*)(xsrow + (j + 192) * 4) = p;
            p.x = pk2(v2.x, v2.y); p.y = pk2(v2.z, v2.w); *(uint2*)(xsrow + (j + 224) * 4) = p;
            p.x = pk2(v3.x, v3.y); p.y = pk2(v3.z, v3.w); *(uint2*)(xsrow + (j + 256) * 4) = p;
            if (has9) {
                p.x = pk2(v4.x, v4.y); p.y = pk2(v4.z, v4.w);
                *(uint2*)(xsrow + (j + 288) * 4) = p;
            }
        }
        if (tid < 64) {                               // zero cols 1168..1183
            const int zr = tid >> 2, seg = tid & 3;
            uint2 z; z.x = 0u; z.y = 0u;
            *(uint2*)(xs + zr * XSW + 1168 + seg * 4) = z;
        }
    }
    __syncthreads();   // B1: slab staged

    // ---- wave w: 8 leaves of mid w (B-frags from slab, outputs in place) ---
    const int colbase = w * 128;
    #pragma unroll
    for (int p = 0; p < 4; ++p) {
        bf16x8 bfrag = *(const bf16x8*)(xs + c * XSW + colbase + p * 32 + g * 8);
        #pragma unroll
        for (int e = 0; e < 2; ++e) {
            const int l = 2 * p + e, leaf = w * 8 + l;
            bf16x8 afrag = *(const bf16x8*)(wsFrag + (WSB_LEAF + leaf) * 512 + lane * 8);
            f32x4 zz = {0.f,0.f,0.f,0.f};
            f32x4 acc = __builtin_amdgcn_mfma_f32_16x16x32_bf16(afrag, bfrag, zz, 0, 0, 0);
            const int po = leaf * 16 + 4 * g;
            float4 S = *(const float4*)(Sl + po);
            float4 T = *(const float4*)(Tl + po);
            uint2 pk;
            pk.x = pk2(bn_act(acc[0], S.x, T.x), bn_act(acc[1], S.y, T.y));
            pk.y = pk2(bn_act(acc[2], S.z, T.z), bn_act(acc[3], S.w, T.w));
            *(uint2*)(xs + c * XSW + colbase + l * 16 + 4 * g) = pk;
        }
    }

    // ---- mid w: K = [hl(128) at colbase, xm(16)+pad at 1024+w*16] ---------
    {
        f32x4 acc0 = {0.f,0.f,0.f,0.f};
        f32x4 acc1 = {0.f,0.f,0.f,0.f};
        const unsigned short* fb = wsFrag + (WSB_MID + w * 10) * 512 + lane * 8;
        #pragma unroll
        for (int s = 0; s < 5; ++s) {
            const int cc = (s < 4) ? (colbase + s * 32) : (1024 + w * 16);
            bf16x8 bfrag = *(const bf16x8*)(xs + c * XSW + cc + g * 8);
            bf16x8 a0 = *(const bf16x8*)(fb + s * 512);
            bf16x8 a1 = *(const bf16x8*)(fb + (5 + s) * 512);
            acc0 = __builtin_amdgcn_mfma_f32_16x16x32_bf16(a0, bfrag, acc0, 0, 0, 0);
            acc1 = __builtin_amdgcn_mfma_f32_16x16x32_bf16(a1, bfrag, acc1, 0, 0, 0);
        }
        #pragma unroll
        for (int tt = 0; tt < 2; ++tt) {
            f32x4 acc = tt ? acc1 : acc0;
            const int po = w * 32 + tt * 16 + 4 * g;
            float4 S = *(const float4*)(Sm + po);
            float4 T = *(const float4*)(Tm + po);
            uint2 pk;
            pk.x = pk2(bn_act(acc[0], S.x, T.x), bn_act(acc[1], S.y, T.y));
            pk.y = pk2(bn_act(acc[2], S.z, T.z), bn_act(acc[3], S.w, T.w));
            *(uint2*)(xs + c * XSW + colbase + tt * 16 + 4 * g) = pk;
        }
    }
    __syncthreads();   // B2: all hm slabs in place

    // ---- root col-tile w (waves 0..3): s=0 from x cols 1152, s=1..8 hm -----
    if (w < 4) {
        const unsigned short* fb = wsFrag + (WSB_ROOT + w * 9) * 512 + lane * 8;
        f32x4 acc = {0.f,0.f,0.f,0.f};
        {
            bf16x8 bfrag = *(const bf16x8*)(xs + c * XSW + 1152 + g * 8);
            bf16x8 a0 = *(const bf16x8*)fb;
            acc = __builtin_amdgcn_mfma_f32_16x16x32_bf16(a0, bfrag, acc, 0, 0, 0);
        }
        #pragma unroll
        for (int s = 1; s <= 8; ++s) {
            bf16x8 bfrag = *(const bf16x8*)(xs + c * XSW + (s - 1) * 128 + g * 8);
            bf16x8 a0 = *(const bf16x8*)(fb + s * 512);
            acc = __builtin_amdgcn_mfma_f32_16x16x32_bf16(a0, bfrag, acc, 0, 0, 0);
        }
        const int po = w * 16 + 4 * g;
        float4 S = *(const float4*)(Sr + po);
        float4 T = *(const float4*)(Tr + po);
        uint2 pk;
        pk.x = pk2(bn_act(acc[0], S.x, T.x), bn_act(acc[1], S.y, T.y));
        pk.y = pk2(bn_act(acc[2], S.z, T.z), bn_act(acc[3], S.w, T.w));
        *(uint2*)(xs + c * XSW + 32 + w * 16 + 4 * g) = pk;
    }
    __syncthreads();   // B3: hr complete

    // ---- head (wave 0): tasks in rows, samples in cols ----
    if (w == 0) {
        f32x4 acc = {0.f,0.f,0.f,0.f};
        #pragma unroll
        for (int s = 0; s < 2; ++s) {
            bf16x8 bfrag = *(const bf16x8*)(xs + c * XSW + 32 + s * 32 + g * 8);
            bf16x8 a0 = *(const bf16x8*)(wsFrag + (WSB_HEAD + s) * 512 + lane * 8);
            acc = __builtin_amdgcn_mfma_f32_16x16x32_bf16(a0, bfrag, acc, 0, 0, 0);
        }
        float* op = out + (size_t)(rowbase + c) * 10 + 4 * g;
        if (g < 2) {
            float2 o1 = {acc[0] + bh[4 * g],     acc[1] + bh[4 * g + 1]};
            float2 o2 = {acc[2] + bh[4 * g + 2], acc[3] + bh[4 * g + 3]};
            *(float2*)op = o1;
            *(float2*)(op + 2) = o2;
        } else if (g == 2) {
            float2 o1 = {acc[0] + bh[8], acc[1] + bh[9]};
            *(float2*)op = o1;
        }
    }
}

extern "C" void kernel_launch(void* const* d_in, const int* in_sizes, int n_in,
                              void* d_out, int out_size, void* d_ws, size_t ws_size,
                              hipStream_t stream) {
    const float* x     = (const float*)d_in[0];
    const float* Wl    = (const float*)d_in[1];
    const float* bl    = (const float*)d_in[2];
    const float* gl    = (const float*)d_in[3];
    const float* betal = (const float*)d_in[4];
    const float* ml    = (const float*)d_in[5];
    const float* vl    = (const float*)d_in[6];
    const float* Wm    = (const float*)d_in[7];
    const float* bm    = (const float*)d_in[8];
    const float* gm    = (const float*)d_in[9];
    const float* betam = (const float*)d_in[10];
    const float* mm    = (const float*)d_in[11];
    const float* vm    = (const float*)d_in[12];
    const float* Wr    = (const float*)d_in[13];
    const float* br    = (const float*)d_in[14];
    const float* gr    = (const float*)d_in[15];
    const float* betar = (const float*)d_in[16];
    const float* mr    = (const float*)d_in[17];
    const float* vr    = (const float*)d_in[18];
    const float* Wh    = (const float*)d_in[19];
    const float* bh    = (const float*)d_in[20];
    float* out = (float*)d_out;

    unsigned short* wsFrag = (unsigned short*)d_ws;
    float* wsST = (float*)((char*)d_ws + WS_ST_BYTE_OFF);

    ontology_prep<<<47, 256, 0, stream>>>(
        Wl, Wm, Wr, Wh, bl, gl, betal, ml, vl, bm, gm, betam, mm, vm,
        br, gr, betar, mr, vr, wsFrag, wsST);

    const int n = in_sizes[0] / 1168;   // 16384
    ontology_mfma<<<n / 16, 512, 0, stream>>>(x, wsFrag, wsST, bh, out);
}